// Round 2
// baseline (299.841 us; speedup 1.0000x reference)
//
#include <hip/hip_runtime.h>

// Reference constants
#define NUM_EMB    8192
#define EMB_DIM    512
#define BATCH_N    16384
#define BD         (BATCH_N * EMB_DIM)   // 8388608 elems in quantized (and diff)
#define TOTAL_OUT  (2 * BD + 1)          // 16777217 fp32 elems in d_out
#define NCHUNK     (TOTAL_OUT / 4)       // 4194304 full float4 chunks (+1 tail)
#define QCHUNK_END (BD / 4)              // 2097152: boundary chunk index
#define NBLOCKS    2048
#define NTHREADS   256
#define NTOTAL     (NBLOCKS * NTHREADS)  // 524288 threads = 8192 waves

// K1/K2 fused: last-done block computes the loss. Device globals persist
// across graph replays: g_partial is overwritten every run; g_done is
// reset to 0 by the last block every run (starts 0 from .bss).
__device__ float g_partial[NBLOCKS];
__device__ int   g_done;

// Native clang vector type — __builtin_nontemporal_store rejects the
// HIP_vector_type wrapper (round-1 compile error).
typedef float nf4 __attribute__((ext_vector_type(4)));
__device__ __forceinline__ void nt_store4(float a, float b, float c, float d,
                                          float4* p) {
    nf4 v = {a, b, c, d};
    __builtin_nontemporal_store(v, (nf4*)p);
}

// Fused kernel. Wave w owns batch rows b = 2w, 2w+1 (same validated chunk
// mapping as before: chunk 128b+i = [row-b elem 4i-1 .. 4i+2], +1 phase
// shift done with __shfl_up). All output stores are nontemporal so the
// 64 MB write stream does not evict W (16 MB) from L2 between the W^2
// pass and the row gathers.
__global__ __launch_bounds__(NTHREADS) void vq_fused(const int* __restrict__ x,
        const float* __restrict__ W, float* __restrict__ out) {
    const int tid  = blockIdx.x * NTHREADS + threadIdx.x;
    const int lane = threadIdx.x & 63;
    const int wid  = threadIdx.x >> 6;         // wave within block
    const int wave = tid >> 6;                 // 0..8191
    float4* out4 = (float4*)out;

    const int b0 = 2 * wave;
    const int b1 = 2 * wave + 1;

    // Index loads first (wave-broadcast; L2-hot after first waves).
    int k0 = x[b0];
    int k1 = x[b1];
    int kp = (b0 > 0) ? x[b0 - 1] : 0;         // prev row's index (unused b0==0)

    // W^2 slice loads — independent, fill the x-load latency. These also
    // warm L2 with the whole codebook right before the gathers.
    const float4* W4 = (const float4*)W;
    float4 sa = W4[tid];
    float4 sb = W4[tid + NTOTAL];

    // Diff region: 2097151 zero chunks, fire-and-forget nt stores that
    // overlap the index/row load latency.
#pragma unroll
    for (int k = 0; k < 4; ++k) {
        int c = QCHUNK_END + 1 + tid + k * NTOTAL;
        if (c < NCHUNK)
            nt_store4(0.f, 0.f, 0.f, 0.f, &out4[c]);
    }
    if (blockIdx.x == 1 && threadIdx.x == 0) {
        out[TOTAL_OUT - 1] = 0.0f;                       // odd tail diff elem
        float w = W[x[BATCH_N - 1] * EMB_DIM + 511];     // boundary chunk
        out4[QCHUNK_END] = make_float4(w, 0.f, 0.f, 0.f);
    }

    // Row gathers: both rows' loads issued back-to-back, stay in flight.
    const float4* R0 = (const float4*)(W + k0 * EMB_DIM);
    const float4* R1 = (const float4*)(W + k1 * EMB_DIM);
    float4 a0 = R0[2 * lane], a1 = R0[2 * lane + 1];
    float4 c0 = R1[2 * lane], c1 = R1[2 * lane + 1];
    float p0 = W[kp * EMB_DIM + 511];          // prev-row elem 511 (broadcast)

    // W^2 partial reduce while the gathers are in flight.
    float s = sa.x*sa.x + sa.y*sa.y + sa.z*sa.z + sa.w*sa.w
            + sb.x*sb.x + sb.y*sb.y + sb.z*sb.z + sb.w*sb.w;
#pragma unroll
    for (int off = 32; off > 0; off >>= 1) s += __shfl_down(s, off, 64);
    __shared__ float ls[NTHREADS / 64];
    if (lane == 0) ls[wid] = s;

    // Row b0: lane l covers row elems 8l..8l+7 -> chunks 128*b0 + 2l, +2l+1.
    {
        float pw = __shfl_up(a1.w, 1, 64);     // lane l-1's elem 8l-1
        float first = (lane == 0) ? p0 : pw;
        int cb = 128 * b0;
        if (b0 != 0 || lane != 0)              // chunk 0 is the loss chunk
            nt_store4(first, a0.x, a0.y, a0.z, &out4[cb + 2 * lane]);
        nt_store4(a0.w, a1.x, a1.y, a1.z, &out4[cb + 2 * lane + 1]);
    }
    // Row b1: its "first" element (row b0 elem 511) is lane 63's a1.w —
    // broadcast via shuffle instead of the old redundant gather load.
    {
        float p1 = __shfl(a1.w, 63, 64);
        float pw = __shfl_up(c1.w, 1, 64);
        float first = (lane == 0) ? p1 : pw;
        int cb = 128 * b1;
        nt_store4(first, c0.x, c0.y, c0.z, &out4[cb + 2 * lane]);
        nt_store4(c0.w, c1.x, c1.y, c1.z, &out4[cb + 2 * lane + 1]);
    }

    // Publish the block partial; the LAST block to arrive computes the loss.
    // Device-scope (agent) atomics: per-XCD L2s are not cross-coherent, so
    // the publish/consume must go through the coherence point (G16).
    __syncthreads();
    __shared__ int lastflag;
    if (threadIdx.x == 0) {
        float part = ls[0] + ls[1] + ls[2] + ls[3];
        __hip_atomic_store(&g_partial[blockIdx.x], part,
                           __ATOMIC_RELEASE, __HIP_MEMORY_SCOPE_AGENT);
        int t = __hip_atomic_fetch_add(&g_done, 1,
                                       __ATOMIC_ACQ_REL, __HIP_MEMORY_SCOPE_AGENT);
        lastflag = (t == NBLOCKS - 1);
    }
    __syncthreads();
    if (lastflag) {
        float s2 = 0.f;
        for (int i = threadIdx.x; i < NBLOCKS; i += NTHREADS)   // 8 indep loads
            s2 += __hip_atomic_load(&g_partial[i], __ATOMIC_RELAXED,
                                    __HIP_MEMORY_SCOPE_AGENT);
        __shared__ float red[NTHREADS];
        red[threadIdx.x] = s2;
        __syncthreads();
        for (int st = NTHREADS / 2; st > 0; st >>= 1) {
            if (threadIdx.x < st) red[threadIdx.x] += red[threadIdx.x + st];
            __syncthreads();
        }
        if (threadIdx.x == 0) {
            float loss = 0.25f * red[0];       // diff loss term is exactly 0
            int k = x[0];
            float4 v = *(const float4*)(W + k * EMB_DIM);
            out4[0] = make_float4(loss, v.x, v.y, v.z);
            __hip_atomic_store(&g_done, 0,     // reset for next graph replay
                               __ATOMIC_RELAXED, __HIP_MEMORY_SCOPE_AGENT);
        }
    }
}

extern "C" void kernel_launch(void* const* d_in, const int* in_sizes, int n_in,
                              void* d_out, int out_size, void* d_ws, size_t ws_size,
                              hipStream_t stream) {
    const int*   x = (const int*)d_in[0];    // int32 indices, 16384
    const float* W = (const float*)d_in[1];  // fp32 codebook, 8192x512
    float* out     = (float*)d_out;          // fp32: [loss | quantized | diff]

    vq_fused<<<NBLOCKS, NTHREADS, 0, stream>>>(x, W, out);
}

// Round 3
// 101.182 us; speedup vs baseline: 2.9634x; 2.9634x over previous
//
#include <hip/hip_runtime.h>

// Reference constants
#define NUM_EMB    8192
#define EMB_DIM    512
#define BATCH_N    16384
#define BD         (BATCH_N * EMB_DIM)   // 8388608 elems in quantized (and diff)
#define TOTAL_OUT  (2 * BD + 1)          // 16777217 fp32 elems in d_out
#define NCHUNK     (TOTAL_OUT / 4)       // 4194304 full float4 chunks (+1 tail)
#define QCHUNK_END (BD / 4)              // 2097152: boundary chunk index
#define NBLOCKS    2048
#define NTHREADS   256
#define NTOTAL     (NBLOCKS * NTHREADS)  // 524288 threads = 8192 waves

__device__ float g_partial[NBLOCKS];     // K1->K2 handoff (stream-order coherent,
                                         // validated in prior session R2/R4)

// ---- K1: per-block partial sums of W^2 (16 MB fp32 stream, ~3 us). Also
// re-warms L2 with W right after the memset's 32 MB write stream. ----
__global__ __launch_bounds__(NTHREADS) void vq_sum(const float* __restrict__ W) {
    int tid = blockIdx.x * NTHREADS + threadIdx.x;
    const float4* W4 = (const float4*)W;
    float4 a = W4[tid];
    float4 b = W4[tid + NTOTAL];
    float s = a.x*a.x + a.y*a.y + a.z*a.z + a.w*a.w
            + b.x*b.x + b.y*b.y + b.z*b.z + b.w*b.w;
#pragma unroll
    for (int off = 32; off > 0; off >>= 1) s += __shfl_down(s, off, 64);
    __shared__ float ls[NTHREADS / 64];
    if ((threadIdx.x & 63) == 0) ls[threadIdx.x >> 6] = s;
    __syncthreads();
    if (threadIdx.x == 0) g_partial[blockIdx.x] = ls[0] + ls[1] + ls[2] + ls[3];
}

// ---- K2: row-streaming writer (quantized region only; diff zeros are done
// by the hipMemsetAsync node at fill-kernel rate). ----
// Wave w owns batch rows b = 2w, 2w+1. For row b it writes chunks
// 128b..128b+127 (chunk 128b+i = [row-b elem 4i-1 .. 4i+2]; i=0 borrows the
// previous row's elem 511). The +1 phase shift is done with __shfl_up, so per
// row each lane does: 2 aligned float4 loads -> 1 shuffle -> 2 aligned stores.
// NORMAL stores only: nontemporal stores measured 1.5x write amplification +
// ~10x throughput loss (round-2 counters: WRITE_SIZE 96.8MB, 523 GB/s) --
// they bypass TCC write-combining. Do not reintroduce.
__global__ __launch_bounds__(NTHREADS) void vq_write(const int* __restrict__ x,
        const float* __restrict__ W, float* __restrict__ out) {
    const int tid  = blockIdx.x * NTHREADS + threadIdx.x;
    const int lane = threadIdx.x & 63;
    const int wave = (tid >> 6);               // 0..8191
    float4* out4 = (float4*)out;

    const int b0 = 2 * wave;
    const int b1 = 2 * wave + 1;

    // Index loads first (wave-uniform -> scalar loads; L2-hot after first waves).
    int k0 = x[b0];
    int k1 = x[b1];
    int kp = (b0 > 0) ? x[b0 - 1] : 0;         // row before b0 (unused for b0==0)

    // Row data: both rows' loads issued back-to-back (independent, stay in flight).
    const float4* R0 = (const float4*)(W + k0 * EMB_DIM);
    const float4* R1 = (const float4*)(W + k1 * EMB_DIM);
    float4 a0 = R0[2 * lane], a1 = R0[2 * lane + 1];
    float4 c0 = R1[2 * lane], c1 = R1[2 * lane + 1];
    float p0 = W[kp * EMB_DIM + 511];          // prev-row elem 511 (broadcast)

    if (blockIdx.x == 1 && threadIdx.x == 0) {
        // Boundary chunk [q_last, 0, 0, 0]; memset covers from elem BD+4 on.
        float w = W[x[BATCH_N - 1] * EMB_DIM + 511];
        out4[QCHUNK_END] = make_float4(w, 0.f, 0.f, 0.f);
    }

    // Row b0: lane l covers row elems 8l..8l+7 -> chunks 128*b0 + 2l, +2l+1.
    {
        float pw = __shfl_up(a1.w, 1, 64);     // lane l-1's elem 8l-1
        float first = (lane == 0) ? p0 : pw;
        int cb = 128 * b0;
        if (b0 != 0 || lane != 0)              // chunk 0 is the loss chunk
            out4[cb + 2 * lane]     = make_float4(first, a0.x, a0.y, a0.z);
        out4[cb + 2 * lane + 1]     = make_float4(a0.w,  a1.x, a1.y, a1.z);
    }
    // Row b1: its "first" element (row b0 elem 511) is lane 63's a1.w --
    // broadcast via shuffle instead of a redundant gather load.
    {
        float p1 = __shfl(a1.w, 63, 64);
        float pw = __shfl_up(c1.w, 1, 64);
        float first = (lane == 0) ? p1 : pw;
        int cb = 128 * b1;
        out4[cb + 2 * lane]         = make_float4(first, c0.x, c0.y, c0.z);
        out4[cb + 2 * lane + 1]     = make_float4(c0.w,  c1.x, c1.y, c1.z);
    }

    // Block 0: reduce partials -> loss, sole writer of chunk 0.
    if (blockIdx.x == 0) {
        __shared__ float red[NTHREADS];
        float s = 0.0f;
        for (int i = threadIdx.x; i < NBLOCKS; i += NTHREADS) s += g_partial[i];
        red[threadIdx.x] = s;
        __syncthreads();
        for (int st = NTHREADS / 2; st > 0; st >>= 1) {
            if (threadIdx.x < st) red[threadIdx.x] += red[threadIdx.x + st];
            __syncthreads();
        }
        if (threadIdx.x == 0) {
            float loss = 0.25f * red[0];       // diff loss term is exactly 0
            int k = x[0];
            float4 v = *(const float4*)(W + k * EMB_DIM);
            out4[0] = make_float4(loss, v.x, v.y, v.z);
        }
    }
}

extern "C" void kernel_launch(void* const* d_in, const int* in_sizes, int n_in,
                              void* d_out, int out_size, void* d_ws, size_t ws_size,
                              hipStream_t stream) {
    const int*   x = (const int*)d_in[0];    // int32 indices, 16384
    const float* W = (const float*)d_in[1];  // fp32 codebook, 8192x512
    float* out     = (float*)d_out;          // fp32: [loss | quantized | diff]

    // Diff region (elems BD+4 .. 2BD inclusive = (BD-3) floats): zero at
    // fill-kernel rate (~6.1 TB/s) instead of in-kernel stores (~2.7 TB/s).
    // Graph-capturable stream-ordered memset node.
    hipMemsetAsync(out + BD + 4, 0, (size_t)(BD - 3) * sizeof(float), stream);
    vq_sum<<<NBLOCKS, NTHREADS, 0, stream>>>(W);
    vq_write<<<NBLOCKS, NTHREADS, 0, stream>>>(x, W, out);
}

// Round 4
// 95.564 us; speedup vs baseline: 3.1376x; 1.0588x over previous
//
#include <hip/hip_runtime.h>

// Reference constants
#define NUM_EMB    8192
#define EMB_DIM    512
#define BATCH_N    16384
#define BD         (BATCH_N * EMB_DIM)   // 8388608 elems in quantized (and diff)
#define TOTAL_OUT  (2 * BD + 1)          // 16777217 fp32 elems in d_out
#define NCHUNK     (TOTAL_OUT / 4)       // 4194304 full float4 chunks (+1 tail)
#define QCHUNK_END (BD / 4)              // 2097152: boundary chunk index
#define NTHREADS   256
#define NB_SUM     2048
#define NTOT_SUM   (NB_SUM * NTHREADS)   // 524288 threads = 8192 waves
#define NB_WR      4096
#define NTOT_WR    (NB_WR * NTHREADS)    // 1048576 threads = 16384 waves

__device__ float g_partial[NB_SUM];      // K1->K2 handoff (stream-order coherent,
                                         // validated in prior session)

// ---- K1: per-block partial sums of W^2 (16 MB fp32 stream, ~3 us). Also
// warms L2/L3 with W right before the gather kernel. ----
__global__ __launch_bounds__(NTHREADS) void vq_sum(const float* __restrict__ W) {
    int tid = blockIdx.x * NTHREADS + threadIdx.x;
    const float4* W4 = (const float4*)W;
    float4 a = W4[tid];
    float4 b = W4[tid + NTOT_SUM];
    float s = a.x*a.x + a.y*a.y + a.z*a.z + a.w*a.w
            + b.x*b.x + b.y*b.y + b.z*b.z + b.w*b.w;
#pragma unroll
    for (int off = 32; off > 0; off >>= 1) s += __shfl_down(s, off, 64);
    __shared__ float ls[NTHREADS / 64];
    if ((threadIdx.x & 63) == 0) ls[threadIdx.x >> 6] = s;
    __syncthreads();
    if (threadIdx.x == 0) g_partial[blockIdx.x] = ls[0] + ls[1] + ls[2] + ls[3];
}

// ---- K2: row-streaming writer, ONE batch row per wave (16384 waves). ----
// Wave w owns batch row b = w. It writes chunks 128b..128b+127 (chunk
// 128b+i = [row-b elem 4i-1 .. 4i+2]; i=0 borrows the previous row's elem
// 511, fetched as a wave-uniform s_load). The +1 phase shift is done with
// __shfl_up, so per row each lane does: 2 aligned float4 loads -> 1
// shuffle -> 2 aligned stores.
// Index chain is scalarized (readfirstlane -> s_load) so the gather uses
// SGPR-base addressing and the scalar unit absorbs the x->W chain latency.
// NORMAL stores only: nontemporal stores measured 1.5x write amplification
// + ~10x throughput loss (round-2). Zero-stores stay in-kernel: round-3
// measured them ~free (overlapped), while a separate memset node cost +6us.
__global__ __launch_bounds__(NTHREADS) void vq_write(const int* __restrict__ x,
        const float* __restrict__ W, float* __restrict__ out) {
    const int tid  = blockIdx.x * NTHREADS + threadIdx.x;
    const int lane = threadIdx.x & 63;
    float4* out4 = (float4*)out;

    // Wave-uniform batch row, forced into an SGPR.
    const int b  = __builtin_amdgcn_readfirstlane(tid >> 6);   // 0..16383
    const int k  = x[b];                        // s_load (uniform addr)
    const int kp = (b > 0) ? x[b - 1] : 0;      // s_load (uniform addr)

    // Gather issued first: 2 float4 per lane, SGPR base + lane offset.
    const float4* R = (const float4*)(W + k * EMB_DIM);
    float4 a0 = R[2 * lane], a1 = R[2 * lane + 1];
    float p0 = W[kp * EMB_DIM + 511];           // s_load, broadcast

    // Diff region: 2097151 zero chunks, 2 per thread, fire-and-forget
    // stores issued while the gather is in flight.
#pragma unroll
    for (int z = 0; z < 2; ++z) {
        int c = QCHUNK_END + 1 + tid + z * NTOT_WR;
        if (c < NCHUNK) out4[c] = make_float4(0.f, 0.f, 0.f, 0.f);
    }
    if (blockIdx.x == 1 && threadIdx.x == 0) {
        out[TOTAL_OUT - 1] = 0.0f;                       // odd tail diff elem
        float w = W[x[BATCH_N - 1] * EMB_DIM + 511];     // boundary chunk
        out4[QCHUNK_END] = make_float4(w, 0.f, 0.f, 0.f);
    }

    // Row b: lane l covers row elems 8l..8l+7 -> chunks 128*b + 2l, +2l+1.
    {
        float pw = __shfl_up(a1.w, 1, 64);      // lane l-1's elem 8l-1
        float first = (lane == 0) ? p0 : pw;
        int cb = 128 * b;
        if (b != 0 || lane != 0)                // chunk 0 is the loss chunk
            out4[cb + 2 * lane]     = make_float4(first, a0.x, a0.y, a0.z);
        out4[cb + 2 * lane + 1]     = make_float4(a0.w,  a1.x, a1.y, a1.z);
    }

    // Block 0: reduce partials -> loss, sole writer of chunk 0.
    if (blockIdx.x == 0) {
        __shared__ float red[NTHREADS];
        float s = 0.0f;
        for (int i = threadIdx.x; i < NB_SUM; i += NTHREADS) s += g_partial[i];
        red[threadIdx.x] = s;
        __syncthreads();
        for (int st = NTHREADS / 2; st > 0; st >>= 1) {
            if (threadIdx.x < st) red[threadIdx.x] += red[threadIdx.x + st];
            __syncthreads();
        }
        if (threadIdx.x == 0) {
            float loss = 0.25f * red[0];        // diff loss term is exactly 0
            int kk = x[0];
            float4 v = *(const float4*)(W + kk * EMB_DIM);
            out4[0] = make_float4(loss, v.x, v.y, v.z);
        }
    }
}

extern "C" void kernel_launch(void* const* d_in, const int* in_sizes, int n_in,
                              void* d_out, int out_size, void* d_ws, size_t ws_size,
                              hipStream_t stream) {
    const int*   x = (const int*)d_in[0];    // int32 indices, 16384
    const float* W = (const float*)d_in[1];  // fp32 codebook, 8192x512
    float* out     = (float*)d_out;          // fp32: [loss | quantized | diff]

    vq_sum<<<NB_SUM, NTHREADS, 0, stream>>>(W);
    vq_write<<<NB_WR, NTHREADS, 0, stream>>>(x, W, out);
}

// Round 5
// 91.955 us; speedup vs baseline: 3.2607x; 1.0392x over previous
//
#include <hip/hip_runtime.h>

// Reference constants
#define NUM_EMB    8192
#define EMB_DIM    512
#define BATCH_N    16384
#define BD         (BATCH_N * EMB_DIM)   // 8388608 elems in quantized (and diff)
#define TOTAL_OUT  (2 * BD + 1)          // 16777217 fp32 elems in d_out
#define NCHUNK     (TOTAL_OUT / 4)       // 4194304 full float4 chunks (+1 tail)
#define QCHUNK_END (BD / 4)              // 2097152: boundary chunk index
#define NTHREADS   256
#define NB_SUM     2048
#define NTOT_SUM   (NB_SUM * NTHREADS)   // 524288 threads = 8192 waves
#define NB_WR      4096
#define NTOT_WR    (NB_WR * NTHREADS)    // 1048576 threads = 16384 waves

__device__ float g_partial[NB_SUM];      // K1->K2 handoff (stream-order coherent,
                                         // validated in prior session)

// ---- K1: per-block partial sums of W^2 (16 MB fp32 stream, ~3 us). Also
// warms L2/L3 with W right before the gather kernel. ----
__global__ __launch_bounds__(NTHREADS) void vq_sum(const float* __restrict__ W) {
    int tid = blockIdx.x * NTHREADS + threadIdx.x;
    const float4* W4 = (const float4*)W;
    float4 a = W4[tid];
    float4 b = W4[tid + NTOT_SUM];
    float s = a.x*a.x + a.y*a.y + a.z*a.z + a.w*a.w
            + b.x*b.x + b.y*b.y + b.z*b.z + b.w*b.w;
#pragma unroll
    for (int off = 32; off > 0; off >>= 1) s += __shfl_down(s, off, 64);
    __shared__ float ls[NTHREADS / 64];
    if ((threadIdx.x & 63) == 0) ls[threadIdx.x >> 6] = s;
    __syncthreads();
    if (threadIdx.x == 0) g_partial[blockIdx.x] = ls[0] + ls[1] + ls[2] + ls[3];
}

// ---- K2: row-streaming writer, ONE batch row per wave (16384 waves). ----
// Wave w owns batch row b = w, writing chunks 128b..128b+127 where chunk
// 128b+i = [row-b elem 4i-1 .. 4i+2] (i=0 borrows prev row's elem 511).
// STRIDE-1 LANE MAPPING (new this round): lane l loads row-chunks l and
// l+64, stores output chunks cb+l and cb+64+l. Every vector load/store
// instruction is a fully-contiguous 1KB wave access (16B/lane, stride-1),
// vs the old 2l/2l+1 mapping whose lanes sat at 32B stride (half-covered
// cache lines -> 2x L1/L2 requests on gather + quantized stores).
// The +1 phase shift is still one __shfl_up per half-row; lane 0 of the
// upper half borrows lane 63's v0.w.
// NORMAL stores only: nontemporal stores measured 1.5x write amplification
// + ~10x throughput loss (round 2). Zero-stores stay in-kernel: a separate
// memset node cost +6us serial (round 3).
__global__ __launch_bounds__(NTHREADS) void vq_write(const int* __restrict__ x,
        const float* __restrict__ W, float* __restrict__ out) {
    const int tid  = blockIdx.x * NTHREADS + threadIdx.x;
    const int lane = threadIdx.x & 63;
    float4* out4 = (float4*)out;

    // Wave-uniform batch row, forced into an SGPR (index chain -> s_loads).
    const int b  = __builtin_amdgcn_readfirstlane(tid >> 6);   // 0..16383
    const int k  = x[b];                        // s_load (uniform addr)
    const int kp = (b > 0) ? x[b - 1] : 0;      // s_load (uniform addr)

    // Gather issued first: 2 contiguous 1KB wave loads, SGPR base.
    const float4* R = (const float4*)(W + k * EMB_DIM);
    float4 v0 = R[lane];                        // row elems 4l .. 4l+3
    float4 v1 = R[lane + 64];                   // row elems 256+4l .. 259+4l
    float p0 = W[kp * EMB_DIM + 511];           // s_load, broadcast

    // Diff region: 2097151 zero chunks, 2 per thread, contiguous
    // fire-and-forget stores issued while the gather is in flight.
#pragma unroll
    for (int z = 0; z < 2; ++z) {
        int c = QCHUNK_END + 1 + tid + z * NTOT_WR;
        if (c < NCHUNK) out4[c] = make_float4(0.f, 0.f, 0.f, 0.f);
    }
    if (blockIdx.x == 1 && threadIdx.x == 0) {
        out[TOTAL_OUT - 1] = 0.0f;                       // odd tail diff elem
        float w = W[x[BATCH_N - 1] * EMB_DIM + 511];     // boundary chunk
        out4[QCHUNK_END] = make_float4(w, 0.f, 0.f, 0.f);
    }

    const int cb = 128 * b;
    // Lower half: chunk cb+l = [elem 4l-1, 4l, 4l+1, 4l+2].
    {
        float pw = __shfl_up(v0.w, 1, 64);      // lane l-1's elem 4l-1
        float first = (lane == 0) ? p0 : pw;
        if (b != 0 || lane != 0)                // chunk 0 is the loss chunk
            out4[cb + lane] = make_float4(first, v0.x, v0.y, v0.z);
    }
    // Upper half: chunk cb+64+l = [elem 255+4l, 256+4l, 257+4l, 258+4l].
    {
        float mid = __shfl(v0.w, 63, 64);       // row elem 255
        float pw  = __shfl_up(v1.w, 1, 64);     // lane l-1's elem 255+4l
        float first = (lane == 0) ? mid : pw;
        out4[cb + 64 + lane] = make_float4(first, v1.x, v1.y, v1.z);
    }

    // Block 0: reduce partials -> loss, sole writer of chunk 0.
    if (blockIdx.x == 0) {
        __shared__ float red[NTHREADS];
        float s = 0.0f;
        for (int i = threadIdx.x; i < NB_SUM; i += NTHREADS) s += g_partial[i];
        red[threadIdx.x] = s;
        __syncthreads();
        for (int st = NTHREADS / 2; st > 0; st >>= 1) {
            if (threadIdx.x < st) red[threadIdx.x] += red[threadIdx.x + st];
            __syncthreads();
        }
        if (threadIdx.x == 0) {
            float loss = 0.25f * red[0];        // diff loss term is exactly 0
            int kk = x[0];
            float4 v = *(const float4*)(W + kk * EMB_DIM);
            out4[0] = make_float4(loss, v.x, v.y, v.z);
        }
    }
}

extern "C" void kernel_launch(void* const* d_in, const int* in_sizes, int n_in,
                              void* d_out, int out_size, void* d_ws, size_t ws_size,
                              hipStream_t stream) {
    const int*   x = (const int*)d_in[0];    // int32 indices, 16384
    const float* W = (const float*)d_in[1];  // fp32 codebook, 8192x512
    float* out     = (float*)d_out;          // fp32: [loss | quantized | diff]

    vq_sum<<<NB_SUM, NTHREADS, 0, stream>>>(W);
    vq_write<<<NB_WR, NTHREADS, 0, stream>>>(x, W, out);
}